// Round 1
// baseline (626.284 us; speedup 1.0000x reference)
//
#include <hip/hip_runtime.h>
#include <hip/hip_bf16.h>

#define NF 128
#define NF2 256
#define NATOMS 100000
#define NGRAPH 128
#define NL 2

#define MT 16          // atoms per block (must be multiple of 16)
#define RV (3*MT)      // 48 v-rows per block
#define SW (NF+8)      // 136  padded stride, 128-wide bufs
#define SW2 (NF2+8)    // 264  padded stride, 256-wide bufs

// swizzled-weight blob sizes (bf16 elements)
#define W1_SZ 16384            // 8ct * 4ks * 64 * 8
#define A1_SZ 32768            // 8ct * 8ks * 64 * 8
#define A2_SZ 32768            // 16ct * 4ks * 64 * 8
#define LAYER_SZ 98304         // w1 + w2 + a1w + a2w

typedef __attribute__((ext_vector_type(8))) short bf16x8;
typedef __attribute__((ext_vector_type(4))) float f32x4;

static __device__ __forceinline__ float bf2f(__hip_bfloat16 x) { return __bfloat162float(x); }
static __device__ __forceinline__ __hip_bfloat16 f2bf(float x) { return __float2bfloat16(x); }

// Pre-swizzle all weights into per-MFMA B-fragment order:
// blob[((ct*nks + ks)*64 + lane)*8 + j] = W[ks*32 + (lane>>4)*8 + j][ct*16 + (lane&15)]
__global__ __launch_bounds__(256)
void prep_weights(const float* __restrict__ w1, const float* __restrict__ w2,
                  const float* __restrict__ a1w, const float* __restrict__ a2w,
                  __hip_bfloat16* __restrict__ blob) {
  int gid = blockIdx.x * 256 + threadIdx.x;           // 24576 total
  int layer = gid / 12288;
  int r = gid - layer * 12288;
  const float* W; int N, nks, g; __hip_bfloat16* dst;
  if (r < 2048)      { W = w1  + layer*NF*NF;  N = NF;  nks = 4; dst = blob + layer*LAYER_SZ;                   g = r; }
  else if (r < 4096) { W = w2  + layer*NF*NF;  N = NF;  nks = 4; dst = blob + layer*LAYER_SZ + W1_SZ;           g = r - 2048; }
  else if (r < 8192) { W = a1w + layer*NF2*NF; N = NF;  nks = 8; dst = blob + layer*LAYER_SZ + 2*W1_SZ;         g = r - 4096; }
  else               { W = a2w + layer*NF*NF2; N = NF2; nks = 4; dst = blob + layer*LAYER_SZ + 2*W1_SZ + A1_SZ; g = r - 8192; }
  int lane = g & 63;
  int ks = (g >> 6) % nks;
  int ct = g / (64 * nks);
  int k0 = ks * 32 + ((lane >> 4) << 3);
  int n  = ct * 16 + (lane & 15);
  __hip_bfloat16* o = dst + (size_t)((ct * nks + ks) * 64 + lane) * 8;
  #pragma unroll
  for (int j = 0; j < 8; ++j) o[j] = f2bf(W[(size_t)(k0 + j) * N + n]);
}

__global__ __launch_bounds__(256, 2)
void fused_equiv(const float* __restrict__ s_g, const float* __restrict__ v_g,
                 const __hip_bfloat16* __restrict__ blob,
                 const float* __restrict__ a1b, const float* __restrict__ a2b,
                 const float* __restrict__ out_w, const float* __restrict__ out_b,
                 float* __restrict__ sc) {
  __shared__ __hip_bfloat16 vcur[RV*SW];    // current v (A for GEMM1)
  __shared__ __hip_bfloat16 vout[RV*SW2];   // [v1 | v2] GEMM1 output
  __shared__ __hip_bfloat16 hbuf[MT*SW2];   // [s | n2] (A for GEMM2); s persists across layers
  __shared__ __hip_bfloat16 h1buf[MT*SW];   // silu output (A for GEMM3)
  __shared__ __hip_bfloat16 gbuf[MT*SW];    // gate

  const int tid  = threadIdx.x;
  const int wave = tid >> 6;
  const int lane = tid & 63;
  const int l15  = lane & 15;
  const int quad = lane >> 4;
  const int a0   = blockIdx.x * MT;

  // ---- stage s -> hbuf[:,0:128] and v -> vcur (fp32 -> bf16) ----
  {
    const float4* s4 = (const float4*)(s_g + (size_t)a0 * NF);
    #pragma unroll
    for (int i = tid; i < MT*NF/4; i += 256) {
      float4 x = s4[i];
      int row = i >> 5;
      int c4  = (i & 31) << 2;
      __hip_bfloat16* p = &hbuf[row*SW2 + c4];
      p[0] = f2bf(x.x); p[1] = f2bf(x.y); p[2] = f2bf(x.z); p[3] = f2bf(x.w);
    }
    const float4* v4 = (const float4*)(v_g + (size_t)a0 * 3 * NF);
    #pragma unroll
    for (int i = tid; i < RV*NF/4; i += 256) {
      float4 x = v4[i];
      int row = i >> 5;
      int c4  = (i & 31) << 2;
      __hip_bfloat16* p = &vcur[row*SW + c4];
      p[0] = f2bf(x.x); p[1] = f2bf(x.y); p[2] = f2bf(x.z); p[3] = f2bf(x.w);
    }
  }
  __syncthreads();

  for (int l = 0; l < NL; ++l) {
    const __hip_bfloat16* lb = blob + l * LAYER_SZ;

    // ---- GEMM1: vcur(48x128) @ [w1|w2](128x256) -> vout(48x256) ----
    {
      bf16x8 bfr[4][4];
      #pragma unroll
      for (int c = 0; c < 4; ++c) {
        int ct = wave*4 + c;                      // 0..15 over combined N=256
        const __hip_bfloat16* wb = (ct < 8) ? (lb + ct*2048) : (lb + W1_SZ + (ct-8)*2048);
        #pragma unroll
        for (int ks = 0; ks < 4; ++ks)
          bfr[c][ks] = *(const bf16x8*)(wb + (ks*64 + lane)*8);
      }
      #pragma unroll
      for (int rt = 0; rt < RV/16; ++rt) {
        const __hip_bfloat16* ar = &vcur[(rt*16 + l15)*SW + (quad<<3)];
        bf16x8 af[4];
        #pragma unroll
        for (int ks = 0; ks < 4; ++ks) af[ks] = *(const bf16x8*)(ar + ks*32);
        f32x4 acc[4] = {};
        #pragma unroll
        for (int ks = 0; ks < 4; ++ks)
          #pragma unroll
          for (int c = 0; c < 4; ++c)
            acc[c] = __builtin_amdgcn_mfma_f32_16x16x32_bf16(af[ks], bfr[c][ks], acc[c], 0, 0, 0);
        #pragma unroll
        for (int c = 0; c < 4; ++c) {
          int col = (wave*4 + c)*16 + l15;
          int rbase = rt*16 + (quad<<2);
          #pragma unroll
          for (int i = 0; i < 4; ++i)
            vout[(rbase+i)*SW2 + col] = f2bf(acc[c][i]);
        }
      }
    }
    __syncthreads();

    // ---- n2 = ||v2||_spatial -> hbuf[:,128:256] ----
    for (int i = tid; i < MT*NF; i += 256) {
      int a = i >> 7, f = i & (NF-1);
      float x0 = bf2f(vout[(a*3+0)*SW2 + NF + f]);
      float x1 = bf2f(vout[(a*3+1)*SW2 + NF + f]);
      float x2 = bf2f(vout[(a*3+2)*SW2 + NF + f]);
      hbuf[a*SW2 + NF + f] = f2bf(sqrtf(x0*x0 + x1*x1 + x2*x2));
    }
    __syncthreads();

    // ---- GEMM2: hbuf(16x256) @ a1w(256x128), +bias, silu -> h1buf ----
    {
      const __hip_bfloat16* wb0 = lb + 2*W1_SZ;
      bf16x8 bfr[2][8];
      #pragma unroll
      for (int c = 0; c < 2; ++c) {
        int ct = wave*2 + c;
        #pragma unroll
        for (int ks = 0; ks < 8; ++ks)
          bfr[c][ks] = *(const bf16x8*)(wb0 + ((ct*8 + ks)*64 + lane)*8);
      }
      #pragma unroll
      for (int rt = 0; rt < MT/16; ++rt) {
        const __hip_bfloat16* ar = &hbuf[(rt*16 + l15)*SW2 + (quad<<3)];
        bf16x8 af[8];
        #pragma unroll
        for (int ks = 0; ks < 8; ++ks) af[ks] = *(const bf16x8*)(ar + ks*32);
        f32x4 acc[2] = {};
        #pragma unroll
        for (int ks = 0; ks < 8; ++ks)
          #pragma unroll
          for (int c = 0; c < 2; ++c)
            acc[c] = __builtin_amdgcn_mfma_f32_16x16x32_bf16(af[ks], bfr[c][ks], acc[c], 0, 0, 0);
        #pragma unroll
        for (int c = 0; c < 2; ++c) {
          int col = (wave*2 + c)*16 + l15;
          float bb = a1b[l*NF + col];
          int rbase = rt*16 + (quad<<2);
          #pragma unroll
          for (int i = 0; i < 4; ++i) {
            float x = acc[c][i] + bb;
            float sl = x / (1.0f + __expf(-x));     // silu
            h1buf[(rbase+i)*SW + col] = f2bf(sl);
          }
        }
      }
    }
    __syncthreads();

    // ---- GEMM3: h1buf(16x128) @ a2w(128x256) -> s_new (hbuf[:,0:128]), g (gbuf) ----
    {
      const __hip_bfloat16* wb0 = lb + 2*W1_SZ + A1_SZ;
      bf16x8 bfr[4][4];
      #pragma unroll
      for (int c = 0; c < 4; ++c) {
        int ct = wave*4 + c;
        #pragma unroll
        for (int ks = 0; ks < 4; ++ks)
          bfr[c][ks] = *(const bf16x8*)(wb0 + ((ct*4 + ks)*64 + lane)*8);
      }
      #pragma unroll
      for (int rt = 0; rt < MT/16; ++rt) {
        const __hip_bfloat16* ar = &h1buf[(rt*16 + l15)*SW + (quad<<3)];
        bf16x8 af[4];
        #pragma unroll
        for (int ks = 0; ks < 4; ++ks) af[ks] = *(const bf16x8*)(ar + ks*32);
        f32x4 acc[4] = {};
        #pragma unroll
        for (int ks = 0; ks < 4; ++ks)
          #pragma unroll
          for (int c = 0; c < 4; ++c)
            acc[c] = __builtin_amdgcn_mfma_f32_16x16x32_bf16(af[ks], bfr[c][ks], acc[c], 0, 0, 0);
        #pragma unroll
        for (int c = 0; c < 4; ++c) {
          int col = (wave*4 + c)*16 + l15;        // 0..255
          float bb = a2b[l*NF2 + col];
          int rbase = rt*16 + (quad<<2);
          if (col < NF) {                          // s_out half (wave-uniform branch)
            #pragma unroll
            for (int i = 0; i < 4; ++i)
              hbuf[(rbase+i)*SW2 + col] = f2bf(acc[c][i] + bb);
          } else {                                 // gate half
            #pragma unroll
            for (int i = 0; i < 4; ++i)
              gbuf[(rbase+i)*SW + (col - NF)] = f2bf(acc[c][i] + bb);
          }
        }
      }
    }
    __syncthreads();

    // ---- gate: vcur = g (broadcast over spatial) * v1 ----
    for (int i = tid; i < RV*NF; i += 256) {
      int rrow = i >> 7, f = i & (NF-1);
      int a = rrow / 3;
      vcur[rrow*SW + f] = f2bf(bf2f(gbuf[a*SW + f]) * bf2f(vout[rrow*SW2 + f]));
    }
    __syncthreads();
  }

  // ---- sc[atom] = dot(s, out_w) + out_b ----
  {
    int a   = tid >> 4;        // 16 threads per atom
    int sub = tid & 15;
    const __hip_bfloat16* hr = &hbuf[a*SW2];
    float p = 0.f;
    #pragma unroll
    for (int j = 0; j < 8; ++j) {
      int f = sub*8 + j;
      p += bf2f(hr[f]) * out_w[f];
    }
    p += __shfl_down(p, 8, 16);
    p += __shfl_down(p, 4, 16);
    p += __shfl_down(p, 2, 16);
    p += __shfl_down(p, 1, 16);
    if (sub == 0) sc[a0 + a] = p + out_b[0];
  }
}

// y[b] = sum_n mask[b,n] * sc[n]
__global__ __launch_bounds__(256)
void reduce_mask(const float* __restrict__ mask, const float* __restrict__ sc,
                 float* __restrict__ out) {
  int b = blockIdx.x;
  const float* mrow = mask + (size_t)b * NATOMS;
  float acc = 0.f;
  for (int n = threadIdx.x; n < NATOMS; n += 256) acc += mrow[n] * sc[n];
  #pragma unroll
  for (int d = 32; d > 0; d >>= 1) acc += __shfl_down(acc, d, 64);
  __shared__ float red[4];
  if ((threadIdx.x & 63) == 0) red[threadIdx.x >> 6] = acc;
  __syncthreads();
  if (threadIdx.x == 0) out[b] = red[0] + red[1] + red[2] + red[3];
}

extern "C" void kernel_launch(void* const* d_in, const int* in_sizes, int n_in,
                              void* d_out, int out_size, void* d_ws, size_t ws_size,
                              hipStream_t stream) {
  const float* s    = (const float*)d_in[0];
  const float* v    = (const float*)d_in[1];
  // d_in[2] = r, unused (dy=False path)
  const float* mask = (const float*)d_in[3];
  const float* w1   = (const float*)d_in[4];
  const float* w2   = (const float*)d_in[5];
  const float* a1w  = (const float*)d_in[6];
  const float* a1b  = (const float*)d_in[7];
  const float* a2w  = (const float*)d_in[8];
  const float* a2b  = (const float*)d_in[9];
  const float* outw = (const float*)d_in[10];
  const float* outb = (const float*)d_in[11];

  __hip_bfloat16* blob = (__hip_bfloat16*)d_ws;                                   // 2*98304 bf16 = 384 KB
  float* sc = (float*)((char*)d_ws + (size_t)NL * LAYER_SZ * sizeof(__hip_bfloat16)); // 400 KB

  prep_weights<<<96, 256, 0, stream>>>(w1, w2, a1w, a2w, blob);
  fused_equiv<<<NATOMS/MT, 256, 0, stream>>>(s, v, blob, a1b, a2b, outw, outb, sc);
  reduce_mask<<<NGRAPH, 256, 0, stream>>>(mask, sc, (float*)d_out);
}

// Round 2
// 553.616 us; speedup vs baseline: 1.1313x; 1.1313x over previous
//
#include <hip/hip_runtime.h>
#include <hip/hip_bf16.h>

#define NF 128
#define NF2 256
#define NATOMS 100000
#define NGRAPH 128
#define NL 2

#define MT 32              // atoms per block
#define NTHR 512           // 8 waves
#define NBLK (NATOMS/MT)   // 3125
#define SW  (NF+4)         // 132: stride for 128-wide bufs (v planes, h1)
#define SWH (NF2+4)        // 260: stride for hbuf [s | n2]

// swizzled-weight blob sizes (bf16 elements)
#define W1_SZ 16384            // 8ct * 4ks * 64 * 8
#define A1_SZ 32768            // 8ct * 8ks * 64 * 8
#define A2_SZ 32768            // 16ct * 4ks * 64 * 8
#define LAYER_SZ 98304

typedef __attribute__((ext_vector_type(8))) short bf16x8;
typedef __attribute__((ext_vector_type(4))) float f32x4;

static __device__ __forceinline__ float bf2f(__hip_bfloat16 x) { return __bfloat162float(x); }
static __device__ __forceinline__ __hip_bfloat16 f2bf(float x) { return __float2bfloat16(x); }
static __device__ __forceinline__ unsigned short f2bfu(float x) {
  __hip_bfloat16 h = __float2bfloat16(x);
  return *(unsigned short*)&h;
}
// 4 bf16 packed 8-byte LDS store
static __device__ __forceinline__ void st4bf(__hip_bfloat16* p, float4 x) {
  ushort4 t = { f2bfu(x.x), f2bfu(x.y), f2bfu(x.z), f2bfu(x.w) };
  *(ushort4*)p = t;
}

// Pre-swizzle weights into per-MFMA B-fragment order:
// blob[((ct*nks + ks)*64 + lane)*8 + j] = W[ks*32 + (lane>>4)*8 + j][ct*16 + (lane&15)]
__global__ __launch_bounds__(256)
void prep_weights(const float* __restrict__ w1, const float* __restrict__ w2,
                  const float* __restrict__ a1w, const float* __restrict__ a2w,
                  __hip_bfloat16* __restrict__ blob) {
  int gid = blockIdx.x * 256 + threadIdx.x;           // 24576 total
  int layer = gid / 12288;
  int r = gid - layer * 12288;
  const float* W; int N, nks, g; __hip_bfloat16* dst;
  if (r < 2048)      { W = w1  + layer*NF*NF;  N = NF;  nks = 4; dst = blob + layer*LAYER_SZ;                   g = r; }
  else if (r < 4096) { W = w2  + layer*NF*NF;  N = NF;  nks = 4; dst = blob + layer*LAYER_SZ + W1_SZ;           g = r - 2048; }
  else if (r < 8192) { W = a1w + layer*NF2*NF; N = NF;  nks = 8; dst = blob + layer*LAYER_SZ + 2*W1_SZ;         g = r - 4096; }
  else               { W = a2w + layer*NF*NF2; N = NF2; nks = 4; dst = blob + layer*LAYER_SZ + 2*W1_SZ + A1_SZ; g = r - 8192; }
  int lane = g & 63;
  int ks = (g >> 6) % nks;
  int ct = g / (64 * nks);
  int k0 = ks * 32 + ((lane >> 4) << 3);
  int n  = ct * 16 + (lane & 15);
  __hip_bfloat16* o = dst + (size_t)((ct * nks + ks) * 64 + lane) * 8;
  #pragma unroll
  for (int j = 0; j < 8; ++j) o[j] = f2bf(W[(size_t)(k0 + j) * N + n]);
}

// Fully fused GatedEquivariant x2 + output head, one block = 32 atoms, 8 waves.
// v kept as 3 atom-major planes so v1/v2 for the same (atom,feature) live in
// the same lane: n2 and the gate are computed in registers (no LDS round-trip).
__global__ __launch_bounds__(NTHR, 4)
void fused_equiv(const float* __restrict__ s_g, const float* __restrict__ v_g,
                 const __hip_bfloat16* __restrict__ blob,
                 const float* __restrict__ a1b, const float* __restrict__ a2b,
                 const float* __restrict__ out_w, const float* __restrict__ out_b,
                 float* __restrict__ sc) {
  __shared__ __hip_bfloat16 vcur[3*MT*SW];   // 3 planes, [c][atom][feat]
  __shared__ __hip_bfloat16 hbuf[MT*SWH];    // [s | n2]
  __shared__ __hip_bfloat16 h1[MT*SW];       // silu output

  const int tid  = threadIdx.x;
  const int wave = tid >> 6;     // 0..7
  const int lane = tid & 63;
  const int l15  = lane & 15;
  const int quad = lane >> 4;
  const int a0   = blockIdx.x * MT;

  // ---- stage s -> hbuf[:,0:128], v -> planes (fp32 -> bf16, 8B LDS stores) ----
  {
    const float4* s4 = (const float4*)(s_g + (size_t)a0 * NF);
    #pragma unroll
    for (int i = tid; i < MT*NF/4; i += NTHR) {
      float4 x = s4[i];
      st4bf(&hbuf[(i >> 5)*SWH + ((i & 31) << 2)], x);
    }
    const float4* v4 = (const float4*)(v_g + (size_t)a0 * 3 * NF);
    #pragma unroll
    for (int i = tid; i < 3*MT*NF/4; i += NTHR) {
      float4 x = v4[i];
      int g = i >> 5;            // global row = atom*3 + c
      int a = g / 3, c = g - 3*a;
      st4bf(&vcur[(c*MT + a)*SW + ((i & 31) << 2)], x);
    }
  }
  __syncthreads();

  f32x4 v1a[3][2];               // v1 accumulators, persist through phases B/C

  for (int l = 0; l < NL; ++l) {
    const __hip_bfloat16* lb = blob + l * LAYER_SZ;

    // ---- Phase A: v @ [w1|w2] as 3 c-plane GEMMs; n2 in registers ----
    {
      bf16x8 w1f[4], w2f[4];
      #pragma unroll
      for (int ks = 0; ks < 4; ++ks) {
        w1f[ks] = *(const bf16x8*)(lb + (wave*4 + ks)*512 + lane*8);
        w2f[ks] = *(const bf16x8*)(lb + W1_SZ + (wave*4 + ks)*512 + lane*8);
      }
      f32x4 v2a[3][2];
      #pragma unroll
      for (int c = 0; c < 3; ++c)
        #pragma unroll
        for (int rt = 0; rt < 2; ++rt) {
          const __hip_bfloat16* ar = &vcur[(c*MT + rt*16 + l15)*SW + (quad << 3)];
          bf16x8 af[4];
          #pragma unroll
          for (int ks = 0; ks < 4; ++ks) af[ks] = *(const bf16x8*)(ar + ks*32);
          f32x4 acc1 = {0.f,0.f,0.f,0.f}, acc2 = {0.f,0.f,0.f,0.f};
          #pragma unroll
          for (int ks = 0; ks < 4; ++ks) {
            acc1 = __builtin_amdgcn_mfma_f32_16x16x32_bf16(af[ks], w1f[ks], acc1, 0, 0, 0);
            acc2 = __builtin_amdgcn_mfma_f32_16x16x32_bf16(af[ks], w2f[ks], acc2, 0, 0, 0);
          }
          v1a[c][rt] = acc1; v2a[c][rt] = acc2;
        }
      // n2 -> hbuf[:,128:256]
      #pragma unroll
      for (int rt = 0; rt < 2; ++rt)
        #pragma unroll
        for (int i = 0; i < 4; ++i) {
          int row = rt*16 + (quad << 2) + i;
          float x0 = v2a[0][rt][i], x1 = v2a[1][rt][i], x2 = v2a[2][rt][i];
          hbuf[row*SWH + NF + wave*16 + l15] = f2bf(sqrtf(x0*x0 + x1*x1 + x2*x2));
        }
    }
    __syncthreads();

    // ---- Phase B: [s|n2](32x256) @ a1w(256x128) + bias, silu -> h1 ----
    {
      const __hip_bfloat16* wb = lb + 2*W1_SZ;
      bf16x8 a1f[8];
      #pragma unroll
      for (int ks = 0; ks < 8; ++ks)
        a1f[ks] = *(const bf16x8*)(wb + (wave*8 + ks)*512 + lane*8);
      int col = wave*16 + l15;
      float bb = a1b[l*NF + col];
      #pragma unroll
      for (int rt = 0; rt < 2; ++rt) {
        const __hip_bfloat16* ar = &hbuf[(rt*16 + l15)*SWH + (quad << 3)];
        f32x4 acc = {0.f,0.f,0.f,0.f};
        #pragma unroll
        for (int ks = 0; ks < 8; ++ks) {
          bf16x8 af = *(const bf16x8*)(ar + ks*32);
          acc = __builtin_amdgcn_mfma_f32_16x16x32_bf16(af, a1f[ks], acc, 0, 0, 0);
        }
        #pragma unroll
        for (int i = 0; i < 4; ++i) {
          float x = acc[i] + bb;
          float sl = x / (1.0f + __expf(-x));
          h1[(rt*16 + (quad << 2) + i)*SW + col] = f2bf(sl);
        }
      }
    }
    __syncthreads();

    // ---- Phase C: h1(32x128) @ a2w(128x256); wave w owns cols {w,w+8}*16 so
    //      g lands in the lane holding v1 -> gate in registers ----
    {
      const __hip_bfloat16* wb = lb + 2*W1_SZ + A1_SZ;
      bf16x8 asf[4], agf[4];
      #pragma unroll
      for (int ks = 0; ks < 4; ++ks) {
        asf[ks] = *(const bf16x8*)(wb + (wave*4 + ks)*512 + lane*8);
        agf[ks] = *(const bf16x8*)(wb + ((wave+8)*4 + ks)*512 + lane*8);
      }
      int col = wave*16 + l15;
      float bbs = a2b[l*NF2 + col];
      float bbg = a2b[l*NF2 + NF + col];
      #pragma unroll
      for (int rt = 0; rt < 2; ++rt) {
        const __hip_bfloat16* ar = &h1[(rt*16 + l15)*SW + (quad << 3)];
        bf16x8 af[4];
        #pragma unroll
        for (int ks = 0; ks < 4; ++ks) af[ks] = *(const bf16x8*)(ar + ks*32);
        f32x4 accs = {0.f,0.f,0.f,0.f}, accg = {0.f,0.f,0.f,0.f};
        #pragma unroll
        for (int ks = 0; ks < 4; ++ks) {
          accs = __builtin_amdgcn_mfma_f32_16x16x32_bf16(af[ks], asf[ks], accs, 0, 0, 0);
          accg = __builtin_amdgcn_mfma_f32_16x16x32_bf16(af[ks], agf[ks], accg, 0, 0, 0);
        }
        #pragma unroll
        for (int i = 0; i < 4; ++i) {
          int row = rt*16 + (quad << 2) + i;
          hbuf[row*SWH + col] = f2bf(accs[i] + bbs);        // s_new
          float g = accg[i] + bbg;
          #pragma unroll
          for (int c = 0; c < 3; ++c)
            vcur[(c*MT + row)*SW + col] = f2bf(g * v1a[c][rt][i]);
        }
      }
    }
    __syncthreads();
  }

  // ---- sc[atom] = dot(s, out_w) + out_b ----
  {
    int a   = tid >> 4;        // 32 atoms x 16 threads
    int sub = tid & 15;
    const __hip_bfloat16* hr = &hbuf[a*SWH];
    float p = 0.f;
    #pragma unroll
    for (int j = 0; j < 8; ++j) {
      int f = sub*8 + j;
      p += bf2f(hr[f]) * out_w[f];
    }
    p += __shfl_down(p, 8, 16);
    p += __shfl_down(p, 4, 16);
    p += __shfl_down(p, 2, 16);
    p += __shfl_down(p, 1, 16);
    if (sub == 0) sc[a0 + a] = p + out_b[0];
  }
}

// Stage 1: partial[b*16+chunk] over 6250-atom chunks (2048 blocks)
__global__ __launch_bounds__(256)
void reduce_partial(const float* __restrict__ mask, const float* __restrict__ sc,
                    float* __restrict__ partial) {
  int b  = blockIdx.x >> 4;
  int ch = blockIdx.x & 15;
  int n0 = ch * (NATOMS/16);
  int n1 = n0 + (NATOMS/16);
  const float* mrow = mask + (size_t)b * NATOMS;
  float acc = 0.f;
  for (int n = n0 + threadIdx.x; n < n1; n += 256) acc += mrow[n] * sc[n];
  #pragma unroll
  for (int d = 32; d > 0; d >>= 1) acc += __shfl_down(acc, d, 64);
  __shared__ float red[4];
  if ((threadIdx.x & 63) == 0) red[threadIdx.x >> 6] = acc;
  __syncthreads();
  if (threadIdx.x == 0) partial[blockIdx.x] = red[0] + red[1] + red[2] + red[3];
}

// Stage 2: out[b] = sum of 16 partials (deterministic)
__global__ void reduce_final(const float* __restrict__ partial, float* __restrict__ out) {
  int b = threadIdx.x;
  if (b < NGRAPH) {
    float s = 0.f;
    #pragma unroll
    for (int k = 0; k < 16; ++k) s += partial[b*16 + k];
    out[b] = s;
  }
}

extern "C" void kernel_launch(void* const* d_in, const int* in_sizes, int n_in,
                              void* d_out, int out_size, void* d_ws, size_t ws_size,
                              hipStream_t stream) {
  const float* s    = (const float*)d_in[0];
  const float* v    = (const float*)d_in[1];
  // d_in[2] = r, unused
  const float* mask = (const float*)d_in[3];
  const float* w1   = (const float*)d_in[4];
  const float* w2   = (const float*)d_in[5];
  const float* a1w  = (const float*)d_in[6];
  const float* a1b  = (const float*)d_in[7];
  const float* a2w  = (const float*)d_in[8];
  const float* a2b  = (const float*)d_in[9];
  const float* outw = (const float*)d_in[10];
  const float* outb = (const float*)d_in[11];

  char* ws = (char*)d_ws;
  __hip_bfloat16* blob = (__hip_bfloat16*)ws;                 // 384 KB
  float* sc      = (float*)(ws + (size_t)NL*LAYER_SZ*2);      // 400 KB
  float* partial = (float*)(ws + (size_t)NL*LAYER_SZ*2 + NATOMS*4); // 8 KB

  prep_weights<<<96, 256, 0, stream>>>(w1, w2, a1w, a2w, blob);
  fused_equiv<<<NBLK, NTHR, 0, stream>>>(s, v, blob, a1b, a2b, outw, outb, sc);
  reduce_partial<<<NGRAPH*16, 256, 0, stream>>>(mask, sc, partial);
  reduce_final<<<1, 128, 0, stream>>>(partial, (float*)d_out);
}

// Round 3
// 528.066 us; speedup vs baseline: 1.1860x; 1.0484x over previous
//
#include <hip/hip_runtime.h>
#include <hip/hip_bf16.h>

#define NF 128
#define NATOMS 100000
#define NGRAPH 128

#define MT 32
#define NTILES (NATOMS/MT)    // 3125
#define GRID 256
#define NTHR 256              // 4 waves

// blob layout per layer (bf16 elems): frags for 32x32x16 MFMA B-operand
#define OW1 0                 // 4ct x 8ks
#define OW2 16384
#define OA1 32768             // 4ct x 16ks
#define OA2 65536             // 8ct x 8ks (ct0-3 = s-half, ct4-7 = gate)
#define LAYER_SZ 98304

typedef __attribute__((ext_vector_type(8)))  short bf16x8;
typedef __attribute__((ext_vector_type(16))) float f32x16;

static __device__ __forceinline__ float bf2f(__hip_bfloat16 x) { return __bfloat162float(x); }
static __device__ __forceinline__ __hip_bfloat16 f2bf(float x) { return __float2bfloat16(x); }
static __device__ __forceinline__ unsigned short f2bfu(float x) {
  __hip_bfloat16 h = __float2bfloat16(x);
  return *(unsigned short*)&h;
}
static __device__ __forceinline__ bf16x8 pack8(float4 lo, float4 hi) {
  union { unsigned short s[8]; bf16x8 v; } u;
  u.s[0]=f2bfu(lo.x); u.s[1]=f2bfu(lo.y); u.s[2]=f2bfu(lo.z); u.s[3]=f2bfu(lo.w);
  u.s[4]=f2bfu(hi.x); u.s[5]=f2bfu(hi.y); u.s[6]=f2bfu(hi.z); u.s[7]=f2bfu(hi.w);
  return u.v;
}

#define GLB(p) ((const __attribute__((address_space(1))) void*)(p))
#define LDS(p) ((__attribute__((address_space(3))) void*)(p))

// A-frag read with XOR swizzle; gr = granules(16B) per row
static __device__ __forceinline__ bf16x8 ldfrag(const __hip_bfloat16* buf, int gr, int row, int gi) {
  return *(const bf16x8*)&buf[(row*gr + (gi ^ (row & 7)))*8];
}
// scalar bf16 store with XOR swizzle
static __device__ __forceinline__ void stb(__hip_bfloat16* buf, int gr, int row, int colq, float v) {
  int gi = colq >> 3, off = colq & 7;
  buf[(row*gr + (gi ^ (row & 7)))*8 + off] = f2bf(v);
}

// Pre-swizzle weights into per-MFMA B-fragment order for 32x32x16:
// frag(lane)[j] = W[ks*16 + (lane>>5)*8 + j][ct*32 + (lane&31)]
__global__ __launch_bounds__(256)
void prep_weights(const float* __restrict__ w1, const float* __restrict__ w2,
                  const float* __restrict__ a1w, const float* __restrict__ a2w,
                  __hip_bfloat16* __restrict__ blob) {
  int gid = blockIdx.x * 256 + threadIdx.x;      // 24576 total
  int lane = gid & 63;
  int g2 = gid >> 6;                             // 0..383
  int layer = g2 / 192;
  int r = g2 - layer * 192;
  const float* W; int N, ct, ks; size_t off;
  if (r < 32)       { W = w1  + layer*16384; N = 128; ct = r >> 3;        ks = r & 7;        off = OW1 + (size_t)r*512; }
  else if (r < 64)  { int q = r-32;  W = w2  + layer*16384; N = 128; ct = q >> 3;  ks = q & 7;  off = OW2 + (size_t)q*512; }
  else if (r < 128) { int q = r-64;  W = a1w + layer*32768; N = 128; ct = q >> 4;  ks = q & 15; off = OA1 + (size_t)q*512; }
  else              { int q = r-128; W = a2w + layer*32768; N = 256; ct = q >> 3;  ks = q & 7;  off = OA2 + (size_t)q*512; }
  int k0 = ks*16 + ((lane >> 5) << 3);
  int n  = ct*32 + (lane & 31);
  __hip_bfloat16* o = blob + (size_t)layer*LAYER_SZ + off + (size_t)lane*8;
  #pragma unroll
  for (int j = 0; j < 8; ++j) o[j] = f2bf(W[(size_t)(k0 + j)*N + n]);
}

// Persistent fused kernel: 256 blocks x 256 thr (4 waves, 1 wave/SIMD).
// All weight fragments register-resident (~320 VGPR); 32x32x16 MFMA.
// Tile staging: global_load_lds fp32 -> LDS stage, convert to XOR-swizzled bf16.
__global__ __launch_bounds__(NTHR, 1)
void fused_equiv(const float* __restrict__ s_g, const float* __restrict__ v_g,
                 const __hip_bfloat16* __restrict__ blob,
                 const float* __restrict__ a1b, const float* __restrict__ a2b,
                 const float* __restrict__ out_w, const float* __restrict__ out_b,
                 float* __restrict__ sc) {
  __shared__ float stage[16384];                    // 64 KB: [s 4096 | v 12288] raw fp32
  __shared__ __hip_bfloat16 vcur[3*MT*NF];          // 24 KB, XOR-swizzled planes
  __shared__ __hip_bfloat16 hbuf[MT*2*NF];          // 16 KB, [s | n2]
  __shared__ __hip_bfloat16 h1[MT*NF];              // 8 KB

  const int tid  = threadIdx.x;
  const int wave = tid >> 6;
  const int lane = tid & 63;
  const int row  = lane & 31;
  const int half = lane >> 5;
  const int col  = wave*32 + row;                   // output column this lane owns

  // ---- load all weight fragments into registers (once per block) ----
  const __hip_bfloat16* L1 = blob;
  const __hip_bfloat16* L2w = blob + LAYER_SZ;
  bf16x8 w1f[8], w2f[8], a1f[16], asf[8], agf[8];   // layer 1
  bf16x8 w2g[8], a1g[16], asg[8];                   // layer 2 (v1/gate not needed)
  #pragma unroll
  for (int ks = 0; ks < 8; ++ks) {
    w1f[ks] = *(const bf16x8*)&L1[OW1 + ((size_t)(wave*8 + ks)*64 + lane)*8];
    w2f[ks] = *(const bf16x8*)&L1[OW2 + ((size_t)(wave*8 + ks)*64 + lane)*8];
    asf[ks] = *(const bf16x8*)&L1[OA2 + ((size_t)(wave*8 + ks)*64 + lane)*8];
    agf[ks] = *(const bf16x8*)&L1[OA2 + ((size_t)((wave+4)*8 + ks)*64 + lane)*8];
    w2g[ks] = *(const bf16x8*)&L2w[OW2 + ((size_t)(wave*8 + ks)*64 + lane)*8];
    asg[ks] = *(const bf16x8*)&L2w[OA2 + ((size_t)(wave*8 + ks)*64 + lane)*8];
  }
  #pragma unroll
  for (int ks = 0; ks < 16; ++ks) {
    a1f[ks] = *(const bf16x8*)&L1[OA1 + ((size_t)(wave*16 + ks)*64 + lane)*8];
    a1g[ks] = *(const bf16x8*)&L2w[OA1 + ((size_t)(wave*16 + ks)*64 + lane)*8];
  }
  const float b1a = a1b[col];            // layer1 a1 bias
  const float b1g = a1b[NF + col];       // layer2 a1 bias
  const float b2s = a2b[col];            // layer1 a2 s-half
  const float b2g = a2b[NF + col];       // layer1 a2 gate
  const float b2s2 = a2b[2*NF + col];    // layer2 a2 s-half
  const float outb = out_b[0];
  const int ha = tid >> 3, hk = tid & 7; // head: 32 atoms x 8 threads
  float owf[16];
  #pragma unroll
  for (int j = 0; j < 16; ++j) owf[j] = out_w[hk*16 + j];

  // ---- staging helper: 64 chunks of 1 KB, 16 per wave ----
  auto stage_issue = [&](int tile) {
    size_t a0 = (size_t)tile * MT;
    #pragma unroll
    for (int i = 0; i < 16; ++i) {
      int g = wave*16 + i;
      const float* src = (g < 16) ? (s_g + a0*NF + g*256 + lane*4)
                                  : (v_g + a0*3*NF + (g-16)*256 + lane*4);
      float* dst = stage + g*256 + lane*4;
      __builtin_amdgcn_global_load_lds(GLB(src), LDS(dst), 16, 0, 0);
    }
  };

  int t = blockIdx.x;
  if (t < NTILES) stage_issue(t);
  __syncthreads();

  for (; t < NTILES; t += GRID) {
    const int a0 = t * MT;

    // ---- convert: stage fp32 -> bf16 swizzled (s->hbuf[:,0:128], v->planes) ----
    {
      int ar = tid >> 3;               // atom row 0..31
      int gbase = (tid & 7) * 2;       // 2 granules
      #pragma unroll
      for (int u = 0; u < 2; ++u) {
        int gi = gbase + u;
        float4 lo = *(const float4*)&stage[ar*NF + gi*8];
        float4 hi = *(const float4*)&stage[ar*NF + gi*8 + 4];
        *(bf16x8*)&hbuf[(ar*32 + (gi ^ (ar & 7)))*8] = pack8(lo, hi);
      }
      #pragma unroll
      for (int c = 0; c < 3; ++c)
        #pragma unroll
        for (int u = 0; u < 2; ++u) {
          int gi = gbase + u;
          float4 lo = *(const float4*)&stage[4096 + ar*384 + c*NF + gi*8];
          float4 hi = *(const float4*)&stage[4096 + ar*384 + c*NF + gi*8 + 4];
          *(bf16x8*)&vcur[c*(MT*NF) + (ar*16 + (gi ^ (ar & 7)))*8] = pack8(lo, hi);
        }
    }
    __syncthreads();

    // prefetch next tile into stage (overlaps with compute below)
    if (t + GRID < NTILES) stage_issue(t + GRID);

    f32x16 v1a[3];

    // ---- L1 Phase A: v @ [w1|w2] per c-plane; n2 in registers ----
    {
      float n2sq[16];
      #pragma unroll
      for (int i = 0; i < 16; ++i) n2sq[i] = 0.f;
      #pragma unroll
      for (int c = 0; c < 3; ++c) {
        const __hip_bfloat16* vb = vcur + c*(MT*NF);
        f32x16 acc1, acc2;
        #pragma unroll
        for (int i = 0; i < 16; ++i) { acc1[i] = 0.f; acc2[i] = 0.f; }
        #pragma unroll
        for (int ks = 0; ks < 8; ++ks) {
          bf16x8 af = ldfrag(vb, 16, row, ks*2 + half);
          acc1 = __builtin_amdgcn_mfma_f32_32x32x16_bf16(af, w1f[ks], acc1, 0, 0, 0);
          acc2 = __builtin_amdgcn_mfma_f32_32x32x16_bf16(af, w2f[ks], acc2, 0, 0, 0);
        }
        v1a[c] = acc1;
        #pragma unroll
        for (int i = 0; i < 16; ++i) n2sq[i] += acc2[i]*acc2[i];
      }
      #pragma unroll
      for (int i = 0; i < 16; ++i) {
        int r = (i & 3) + 8*(i >> 2) + 4*half;
        stb(hbuf, 32, r, NF + col, sqrtf(n2sq[i]));
      }
    }
    __syncthreads();

    // ---- L1 Phase B: [s|n2] @ a1w + bias, silu -> h1 ----
    {
      f32x16 h;
      #pragma unroll
      for (int i = 0; i < 16; ++i) h[i] = 0.f;
      #pragma unroll
      for (int ks = 0; ks < 16; ++ks) {
        bf16x8 af = ldfrag(hbuf, 32, row, ks*2 + half);
        h = __builtin_amdgcn_mfma_f32_32x32x16_bf16(af, a1f[ks], h, 0, 0, 0);
      }
      #pragma unroll
      for (int i = 0; i < 16; ++i) {
        int r = (i & 3) + 8*(i >> 2) + 4*half;
        float x = h[i] + b1a;
        stb(h1, 16, r, col, x / (1.0f + __expf(-x)));
      }
    }
    __syncthreads();

    // ---- L1 Phase C: h1 @ a2w -> s1 (hbuf) + gate*v1 (vcur, registers) ----
    {
      f32x16 hs, hg;
      #pragma unroll
      for (int i = 0; i < 16; ++i) { hs[i] = 0.f; hg[i] = 0.f; }
      #pragma unroll
      for (int ks = 0; ks < 8; ++ks) {
        bf16x8 af = ldfrag(h1, 16, row, ks*2 + half);
        hs = __builtin_amdgcn_mfma_f32_32x32x16_bf16(af, asf[ks], hs, 0, 0, 0);
        hg = __builtin_amdgcn_mfma_f32_32x32x16_bf16(af, agf[ks], hg, 0, 0, 0);
      }
      #pragma unroll
      for (int i = 0; i < 16; ++i) {
        int r = (i & 3) + 8*(i >> 2) + 4*half;
        stb(hbuf, 32, r, col, hs[i] + b2s);
        float g = hg[i] + b2g;
        stb(vcur,           16, r, col, g * v1a[0][i]);
        stb(vcur +   MT*NF, 16, r, col, g * v1a[1][i]);
        stb(vcur + 2*MT*NF, 16, r, col, g * v1a[2][i]);
      }
    }
    __syncthreads();

    // ---- L2 Phase A: v' @ w2 only (v1 of last layer unused) -> n2 ----
    {
      float n2sq[16];
      #pragma unroll
      for (int i = 0; i < 16; ++i) n2sq[i] = 0.f;
      #pragma unroll
      for (int c = 0; c < 3; ++c) {
        const __hip_bfloat16* vb = vcur + c*(MT*NF);
        f32x16 acc2;
        #pragma unroll
        for (int i = 0; i < 16; ++i) acc2[i] = 0.f;
        #pragma unroll
        for (int ks = 0; ks < 8; ++ks) {
          bf16x8 af = ldfrag(vb, 16, row, ks*2 + half);
          acc2 = __builtin_amdgcn_mfma_f32_32x32x16_bf16(af, w2g[ks], acc2, 0, 0, 0);
        }
        #pragma unroll
        for (int i = 0; i < 16; ++i) n2sq[i] += acc2[i]*acc2[i];
      }
      #pragma unroll
      for (int i = 0; i < 16; ++i) {
        int r = (i & 3) + 8*(i >> 2) + 4*half;
        stb(hbuf, 32, r, NF + col, sqrtf(n2sq[i]));
      }
    }
    __syncthreads();

    // ---- L2 Phase B ----
    {
      f32x16 h;
      #pragma unroll
      for (int i = 0; i < 16; ++i) h[i] = 0.f;
      #pragma unroll
      for (int ks = 0; ks < 16; ++ks) {
        bf16x8 af = ldfrag(hbuf, 32, row, ks*2 + half);
        h = __builtin_amdgcn_mfma_f32_32x32x16_bf16(af, a1g[ks], h, 0, 0, 0);
      }
      #pragma unroll
      for (int i = 0; i < 16; ++i) {
        int r = (i & 3) + 8*(i >> 2) + 4*half;
        float x = h[i] + b1g;
        stb(h1, 16, r, col, x / (1.0f + __expf(-x)));
      }
    }
    __syncthreads();

    // ---- L2 Phase C: s2 only -> hbuf s-half ----
    {
      f32x16 hs;
      #pragma unroll
      for (int i = 0; i < 16; ++i) hs[i] = 0.f;
      #pragma unroll
      for (int ks = 0; ks < 8; ++ks) {
        bf16x8 af = ldfrag(h1, 16, row, ks*2 + half);
        hs = __builtin_amdgcn_mfma_f32_32x32x16_bf16(af, asg[ks], hs, 0, 0, 0);
      }
      #pragma unroll
      for (int i = 0; i < 16; ++i) {
        int r = (i & 3) + 8*(i >> 2) + 4*half;
        stb(hbuf, 32, r, col, hs[i] + b2s2);
      }
    }
    __syncthreads();

    // ---- head: sc[atom] = dot(s2, out_w) + out_b ----
    {
      float p = 0.f;
      #pragma unroll
      for (int j = 0; j < 16; ++j) {
        int f = hk*16 + j;
        p += bf2f(hbuf[(ha*32 + ((f >> 3) ^ (ha & 7)))*8 + (f & 7)]) * owf[j];
      }
      p += __shfl_down(p, 4, 8);
      p += __shfl_down(p, 2, 8);
      p += __shfl_down(p, 1, 8);
      if (hk == 0) sc[a0 + ha] = p + outb;
    }
    __syncthreads();   // protects hbuf/stage before next convert
  }
}

// Stage 1: partial[b*16+chunk] over 6250-atom chunks (2048 blocks)
__global__ __launch_bounds__(256)
void reduce_partial(const float* __restrict__ mask, const float* __restrict__ sc,
                    float* __restrict__ partial) {
  int b  = blockIdx.x >> 4;
  int ch = blockIdx.x & 15;
  int n0 = ch * (NATOMS/16);
  int n1 = n0 + (NATOMS/16);
  const float* mrow = mask + (size_t)b * NATOMS;
  float acc = 0.f;
  for (int n = n0 + threadIdx.x; n < n1; n += 256) acc += mrow[n] * sc[n];
  #pragma unroll
  for (int d = 32; d > 0; d >>= 1) acc += __shfl_down(acc, d, 64);
  __shared__ float red[4];
  if ((threadIdx.x & 63) == 0) red[threadIdx.x >> 6] = acc;
  __syncthreads();
  if (threadIdx.x == 0) partial[blockIdx.x] = red[0] + red[1] + red[2] + red[3];
}

__global__ void reduce_final(const float* __restrict__ partial, float* __restrict__ out) {
  int b = threadIdx.x;
  if (b < NGRAPH) {
    float s = 0.f;
    #pragma unroll
    for (int k = 0; k < 16; ++k) s += partial[b*16 + k];
    out[b] = s;
  }
}

extern "C" void kernel_launch(void* const* d_in, const int* in_sizes, int n_in,
                              void* d_out, int out_size, void* d_ws, size_t ws_size,
                              hipStream_t stream) {
  const float* s    = (const float*)d_in[0];
  const float* v    = (const float*)d_in[1];
  // d_in[2] = r, unused
  const float* mask = (const float*)d_in[3];
  const float* w1   = (const float*)d_in[4];
  const float* w2   = (const float*)d_in[5];
  const float* a1w  = (const float*)d_in[6];
  const float* a1b  = (const float*)d_in[7];
  const float* a2w  = (const float*)d_in[8];
  const float* a2b  = (const float*)d_in[9];
  const float* outw = (const float*)d_in[10];
  const float* outb = (const float*)d_in[11];

  char* ws = (char*)d_ws;
  __hip_bfloat16* blob = (__hip_bfloat16*)ws;                      // 384 KB
  float* sc      = (float*)(ws + (size_t)2*LAYER_SZ*2);            // 400 KB
  float* partial = (float*)(ws + (size_t)2*LAYER_SZ*2 + NATOMS*4); // 8 KB

  prep_weights<<<96, 256, 0, stream>>>(w1, w2, a1w, a2w, blob);
  fused_equiv<<<GRID, NTHR, 0, stream>>>(s, v, blob, a1b, a2b, outw, outb, sc);
  reduce_partial<<<NGRAPH*16, 256, 0, stream>>>(mask, sc, partial);
  reduce_final<<<1, 128, 0, stream>>>(partial, (float*)d_out);
}